// Round 1
// baseline (1644.585 us; speedup 1.0000x reference)
//
#include <hip/hip_runtime.h>
#include <hip/hip_bf16.h>

typedef __bf16 bf16_t;
typedef __bf16 bf16x4 __attribute__((ext_vector_type(4)));
typedef __bf16 bf16x8 __attribute__((ext_vector_type(8)));
typedef float f32x4 __attribute__((ext_vector_type(4)));

#define NTOK 4096   // B*T = 8*512
#define TT   512
#define HH   1024
#define VV   32000

#define BM 128
#define BN 128
#define BK 32
#define LDK 40      // BK + 8 bf16 pad -> 80B row stride, 16B-aligned, conflict-light

// ---------------------------------------------------------------------------
// Fused GEMM + logsumexp partial + selected-logit gather.
// logits[m][n] = sum_h X[m][h] * W[n][h];  S[m] += sum_n exp(logit);
// SEL[m] = logit[m][ids[m]] when this block's N-range covers it.
// ---------------------------------------------------------------------------
__global__ __launch_bounds__(256)
void grpo_gemm_lse(const float* __restrict__ X, const float* __restrict__ W,
                   const int* __restrict__ ids,
                   float* __restrict__ S, float* __restrict__ SEL)
{
    __shared__ bf16_t lds_a[BM][LDK];
    __shared__ bf16_t lds_b[BN][LDK];

    const int tid  = threadIdx.x;
    const int lane = tid & 63;
    const int wv   = tid >> 6;
    const int wr   = wv >> 1;       // wave row (2x2 wave grid, each 64x64)
    const int wc   = wv & 1;
    const int g    = lane >> 4;     // 4-lane-group id 0..3
    const int l16  = lane & 15;

    const int m0 = blockIdx.x * BM; // token tile
    const int n0 = blockIdx.y * BN; // vocab tile

    f32x4 acc[4][4];
#pragma unroll
    for (int m = 0; m < 4; ++m)
#pragma unroll
        for (int n = 0; n < 4; ++n)
            acc[m][n] = (f32x4)0.0f;

    for (int k0 = 0; k0 < HH; k0 += BK) {
        // ---- stage A (tokens) and B (vocab rows) as bf16 into LDS ----
#pragma unroll
        for (int i = 0; i < 4; ++i) {
            int cid = i * 256 + tid;        // 0..1023 float4-chunks
            int row = cid >> 3;             // 0..127
            int c4  = (cid & 7) << 2;       // 0,4,...,28
            f32x4 va = *(const f32x4*)(X + (size_t)(m0 + row) * HH + k0 + c4);
            f32x4 vb = *(const f32x4*)(W + (size_t)(n0 + row) * HH + k0 + c4);
            bf16x4 ba, bb;
#pragma unroll
            for (int e = 0; e < 4; ++e) {
                ba[e] = (bf16_t)va[e];
                bb[e] = (bf16_t)vb[e];
            }
            *(bf16x4*)&lds_a[row][c4] = ba;
            *(bf16x4*)&lds_b[row][c4] = bb;
        }
        __syncthreads();

        // ---- fragments: 8 contiguous bf16 along K (identical k-map for A,B) ----
        bf16x8 af[4], bfr[4];
#pragma unroll
        for (int m = 0; m < 4; ++m)
            af[m] = *(const bf16x8*)&lds_a[wr * 64 + m * 16 + l16][g * 8];
#pragma unroll
        for (int n = 0; n < 4; ++n)
            bfr[n] = *(const bf16x8*)&lds_b[wc * 64 + n * 16 + l16][g * 8];

#pragma unroll
        for (int m = 0; m < 4; ++m)
#pragma unroll
            for (int n = 0; n < 4; ++n)
                acc[m][n] = __builtin_amdgcn_mfma_f32_16x16x32_bf16(
                    af[m], bfr[n], acc[m][n], 0, 0, 0);

        __syncthreads();
    }

    // ---- epilogue: exp-sum reduce per token row + selected logit capture ----
    // D layout (verified): row = 4*g + j, col = l16 within each 16x16 frag.
#pragma unroll
    for (int m = 0; m < 4; ++m) {
#pragma unroll
        for (int j = 0; j < 4; ++j) {
            int row = m0 + wr * 64 + m * 16 + g * 4 + j;
            float s = 0.f;
#pragma unroll
            for (int n = 0; n < 4; ++n)
                s += __expf(acc[m][n][j]);
            // reduce across the 16 lanes (same row, different cols)
            s += __shfl_xor(s, 1, 64);
            s += __shfl_xor(s, 2, 64);
            s += __shfl_xor(s, 4, 64);
            s += __shfl_xor(s, 8, 64);
            if (l16 == 0) atomicAdd(&S[row], s);

            int id   = ids[row];
            int base = n0 + wc * 64 + l16;
#pragma unroll
            for (int n = 0; n < 4; ++n)
                if (id == base + n * 16) SEL[row] = acc[m][n][j];
        }
    }
}

// ---------------------------------------------------------------------------
// Zero the per-token accumulators (harness does not re-poison between replays).
// ---------------------------------------------------------------------------
__global__ void grpo_init(float* __restrict__ p)
{
    p[blockIdx.x * 1024 + threadIdx.x] = 0.f;  // 16 blocks x 1024 = 16384
}

// ---------------------------------------------------------------------------
// logp, exact rank-819 threshold, k3 KL, final reductions -> 3 scalars.
// ---------------------------------------------------------------------------
__global__ __launch_bounds__(1024)
void grpo_finalize(const float* __restrict__ S_p, const float* __restrict__ SEL_p,
                   const float* __restrict__ S_r, const float* __restrict__ SEL_r,
                   const float* __restrict__ am, const float* __restrict__ adv,
                   float* __restrict__ out)
{
    __shared__ float lp_p[NTOK];
    __shared__ float lp_r[NTOK];
    __shared__ float thr_sh;
    __shared__ double red[3][16];

    const int tid = threadIdx.x;

    for (int i = tid; i < NTOK; i += 1024) {
        lp_p[i] = SEL_p[i] - logf(S_p[i]);
        lp_r[i] = SEL_r[i] - logf(S_r[i]);
    }
    __syncthreads();

    // ---- threshold = sorted(lp_r)[818]  (k = max(1, int(4096*0.2)) = 819) ----
    {
        float v[4];
        int lt[4] = {0, 0, 0, 0}, eq[4] = {0, 0, 0, 0};
#pragma unroll
        for (int q = 0; q < 4; ++q) v[q] = lp_r[tid + q * 1024];
        for (int j = 0; j < NTOK; ++j) {
            float u = lp_r[j];  // broadcast read
#pragma unroll
            for (int q = 0; q < 4; ++q) {
                lt[q] += (u < v[q]);
                eq[q] += (u == v[q]);
            }
        }
#pragma unroll
        for (int q = 0; q < 4; ++q)
            if (lt[q] <= 818 && 818 < lt[q] + eq[q]) thr_sh = v[q];
    }
    __syncthreads();
    const float thr = thr_sh;

    // ---- per-token loss; coef_1 == coef_2 == 1 exactly -> ppo term = -adv ----
    double s_loss = 0.0, s_kl = 0.0, s_am = 0.0;
    for (int i = tid; i < NTOK; i += 1024) {
        float a  = am[i];
        float pr = lp_r[i], pp = lp_p[i];
        float lr = pr - pp;
        float k3 = expf(lr) - lr - 1.0f;
        float kl = (pr <= thr) ? k3 * 5.0f : 0.0f;   // scale = 1/0.2
        float ad = adv[i / TT];
        float ptl = -ad + 0.04f * kl;                 // BETA = 0.04
        s_loss += (double)(ptl * a);
        s_kl   += (double)(kl * a);
        s_am   += (double)a;
    }
#pragma unroll
    for (int off = 32; off; off >>= 1) {
        s_loss += __shfl_down(s_loss, off, 64);
        s_kl   += __shfl_down(s_kl,   off, 64);
        s_am   += __shfl_down(s_am,   off, 64);
    }
    const int wid = tid >> 6;
    if ((tid & 63) == 0) {
        red[0][wid] = s_loss;
        red[1][wid] = s_kl;
        red[2][wid] = s_am;
    }
    __syncthreads();
    if (tid == 0) {
        double L = 0, K = 0, A = 0;
        for (int w = 0; w < 16; ++w) { L += red[0][w]; K += red[1][w]; A += red[2][w]; }
        double norm = A < 1.0 ? 1.0 : A;
        out[0] = (float)(L / norm);
        out[1] = (float)(K / norm);
        out[2] = 0.0f;   // coef_1 == 1 exactly -> never clipped
    }
}

extern "C" void kernel_launch(void* const* d_in, const int* in_sizes, int n_in,
                              void* d_out, int out_size, void* d_ws, size_t ws_size,
                              hipStream_t stream)
{
    const float* X   = (const float*)d_in[0];  // _input (8,512,1024)
    const float* W   = (const float*)d_in[1];  // lin_weight (32000,1024)
    const int*   ids = (const int*)  d_in[2];  // selected_token_ids (8,512)
    const float* am  = (const float*)d_in[3];  // attention_mask (8,512)
    const float* adv = (const float*)d_in[4];  // advantages (8,)
    const float* Xr  = (const float*)d_in[5];  // ref_input
    const float* Wr  = (const float*)d_in[6];  // ref_weight
    float* out = (float*)d_out;

    float* S_p   = (float*)d_ws;       // [4096] policy sumexp
    float* S_r   = S_p + NTOK;         // [4096] ref sumexp
    float* SEL_p = S_r + NTOK;         // [4096] policy selected logit
    float* SEL_r = SEL_p + NTOK;       // [4096] ref selected logit

    hipLaunchKernelGGL(grpo_init, dim3(16), dim3(1024), 0, stream, S_p);

    dim3 grid(NTOK / BM, VV / BN);     // x = m-tile (fast) so W panel reuses in L2
    hipLaunchKernelGGL(grpo_gemm_lse, grid, dim3(256), 0, stream, X,  W,  ids, S_p, SEL_p);
    hipLaunchKernelGGL(grpo_gemm_lse, grid, dim3(256), 0, stream, Xr, Wr, ids, S_r, SEL_r);

    hipLaunchKernelGGL(grpo_finalize, dim3(1), dim3(1024), 0, stream,
                       S_p, SEL_p, S_r, SEL_r, am, adv, out);
}

// Round 2
// 889.269 us; speedup vs baseline: 1.8494x; 1.8494x over previous
//
#include <hip/hip_runtime.h>
#include <hip/hip_bf16.h>

typedef __bf16 bf16_t;
typedef __bf16 bf16x4 __attribute__((ext_vector_type(4)));
typedef __bf16 bf16x8 __attribute__((ext_vector_type(8)));
typedef float f32x4 __attribute__((ext_vector_type(4)));

#define NTOK 4096   // B*T = 8*512
#define TT   512
#define HH   1024
#define VV   32000

#define BM 128
#define BN 128
#define BK 32

#define GLOBAL_AS(p) ((const __attribute__((address_space(1))) void*)(const void*)(p))
#define LDS_AS(p)    ((__attribute__((address_space(3))) void*)(void*)(p))

// ---------------------------------------------------------------------------
// f32 -> bf16 bulk convert (memory-bound pre-pass).
// ---------------------------------------------------------------------------
__global__ __launch_bounds__(256)
void grpo_cvt_bf16(const float* __restrict__ src, bf16_t* __restrict__ dst, int n4)
{
    int i = blockIdx.x * 256 + threadIdx.x;
    const int stride = gridDim.x * 256;
    for (; i < n4; i += stride) {
        f32x4 v = *(const f32x4*)(src + (size_t)i * 4);
        bf16x4 b;
#pragma unroll
        for (int e = 0; e < 4; ++e) b[e] = (bf16_t)v[e];
        *(bf16x4*)(dst + (size_t)i * 4) = b;
    }
}

// ---------------------------------------------------------------------------
// m97-structure GEMM + logsumexp partial + selected-logit gather (bf16 inputs).
// logits[m][n] = sum_h X[m][h]*W[n][h]; S[m] += sum_n exp(logit); SEL gather.
// ---------------------------------------------------------------------------
__global__ __launch_bounds__(256)
void grpo_gemm_lse_bf16(const bf16_t* __restrict__ Xb, const bf16_t* __restrict__ Wb,
                        const int* __restrict__ ids,
                        float* __restrict__ S, float* __restrict__ SEL)
{
    __shared__ bf16_t lds_a[BM][BK];   // linear [row][k], 64B rows (global_load_lds dest)
    __shared__ bf16_t lds_b[BN][BK];

    const int tid  = threadIdx.x;
    const int lane = tid & 63;
    const int wv   = tid >> 6;
    const int wr   = wv >> 1;          // 2x2 wave grid, each wave owns 64x64
    const int wc   = wv & 1;
    const int g    = lane >> 4;
    const int l16  = lane & 15;

    const int m0 = blockIdx.x * BM;
    const int n0 = blockIdx.y * BN;

    f32x4 acc[4][4];
#pragma unroll
    for (int m = 0; m < 4; ++m)
#pragma unroll
        for (int n = 0; n < 4; ++n)
            acc[m][n] = (f32x4)0.0f;

    for (int k0 = 0; k0 < HH; k0 += BK) {
        // ---- async stage: 512 chunks of 16B per tile, 2 issues/thread/tile ----
#pragma unroll
        for (int i = 0; i < 2; ++i) {
            const int c    = i * 256 + tid;     // chunk id 0..511
            const int row  = c >> 2;
            const int slot = c & 3;             // 8 bf16 per slot
            const bf16_t* ga = Xb + (size_t)(m0 + row) * HH + k0 + slot * 8;
            const bf16_t* gb = Wb + (size_t)(n0 + row) * HH + k0 + slot * 8;
            // wave-uniform LDS base; HW writes base + lane*16
            bf16_t* la = &lds_a[0][0] + (size_t)(i * 256 + wv * 64) * 8;
            bf16_t* lb = &lds_b[0][0] + (size_t)(i * 256 + wv * 64) * 8;
            __builtin_amdgcn_global_load_lds(GLOBAL_AS(ga), LDS_AS(la), 16, 0, 0);
            __builtin_amdgcn_global_load_lds(GLOBAL_AS(gb), LDS_AS(lb), 16, 0, 0);
        }
        __syncthreads();   // drains vmcnt -> staging complete

        bf16x8 af[4], bfr[4];
#pragma unroll
        for (int m = 0; m < 4; ++m)
            af[m] = *(const bf16x8*)&lds_a[wr * 64 + m * 16 + l16][g * 8];
#pragma unroll
        for (int n = 0; n < 4; ++n)
            bfr[n] = *(const bf16x8*)&lds_b[wc * 64 + n * 16 + l16][g * 8];

#pragma unroll
        for (int m = 0; m < 4; ++m)
#pragma unroll
            for (int n = 0; n < 4; ++n)
                acc[m][n] = __builtin_amdgcn_mfma_f32_16x16x32_bf16(
                    af[m], bfr[n], acc[m][n], 0, 0, 0);

        __syncthreads();   // before next-iter overwrite
    }

    // ---- epilogue: exp-sum per token row + selected logit ----
#pragma unroll
    for (int m = 0; m < 4; ++m) {
#pragma unroll
        for (int j = 0; j < 4; ++j) {
            int row = m0 + wr * 64 + m * 16 + g * 4 + j;
            float s = 0.f;
#pragma unroll
            for (int n = 0; n < 4; ++n)
                s += __expf(acc[m][n][j]);
            s += __shfl_xor(s, 1, 64);
            s += __shfl_xor(s, 2, 64);
            s += __shfl_xor(s, 4, 64);
            s += __shfl_xor(s, 8, 64);
            if (l16 == 0) atomicAdd(&S[row], s);

            int id   = ids[row];
            int base = n0 + wc * 64 + l16;
#pragma unroll
            for (int n = 0; n < 4; ++n)
                if (id == base + n * 16) SEL[row] = acc[m][n][j];
        }
    }
}

// ---------------------------------------------------------------------------
// Fallback GEMM (f32 inputs, reg-staged convert) — used only if ws too small.
// ---------------------------------------------------------------------------
#define LDK 40
__global__ __launch_bounds__(256)
void grpo_gemm_lse_f32(const float* __restrict__ X, const float* __restrict__ W,
                       const int* __restrict__ ids,
                       float* __restrict__ S, float* __restrict__ SEL)
{
    __shared__ bf16_t lds_a[BM][LDK];
    __shared__ bf16_t lds_b[BN][LDK];

    const int tid  = threadIdx.x;
    const int lane = tid & 63;
    const int wv   = tid >> 6;
    const int wr   = wv >> 1;
    const int wc   = wv & 1;
    const int g    = lane >> 4;
    const int l16  = lane & 15;

    const int m0 = blockIdx.x * BM;
    const int n0 = blockIdx.y * BN;

    f32x4 acc[4][4];
#pragma unroll
    for (int m = 0; m < 4; ++m)
#pragma unroll
        for (int n = 0; n < 4; ++n)
            acc[m][n] = (f32x4)0.0f;

    for (int k0 = 0; k0 < HH; k0 += BK) {
#pragma unroll
        for (int i = 0; i < 4; ++i) {
            int cid = i * 256 + tid;
            int row = cid >> 3;
            int c4  = (cid & 7) << 2;
            f32x4 va = *(const f32x4*)(X + (size_t)(m0 + row) * HH + k0 + c4);
            f32x4 vb = *(const f32x4*)(W + (size_t)(n0 + row) * HH + k0 + c4);
            bf16x4 ba, bb;
#pragma unroll
            for (int e = 0; e < 4; ++e) { ba[e] = (bf16_t)va[e]; bb[e] = (bf16_t)vb[e]; }
            *(bf16x4*)&lds_a[row][c4] = ba;
            *(bf16x4*)&lds_b[row][c4] = bb;
        }
        __syncthreads();

        bf16x8 af[4], bfr[4];
#pragma unroll
        for (int m = 0; m < 4; ++m)
            af[m] = *(const bf16x8*)&lds_a[wr * 64 + m * 16 + l16][g * 8];
#pragma unroll
        for (int n = 0; n < 4; ++n)
            bfr[n] = *(const bf16x8*)&lds_b[wc * 64 + n * 16 + l16][g * 8];

#pragma unroll
        for (int m = 0; m < 4; ++m)
#pragma unroll
            for (int n = 0; n < 4; ++n)
                acc[m][n] = __builtin_amdgcn_mfma_f32_16x16x32_bf16(
                    af[m], bfr[n], acc[m][n], 0, 0, 0);
        __syncthreads();
    }

#pragma unroll
    for (int m = 0; m < 4; ++m) {
#pragma unroll
        for (int j = 0; j < 4; ++j) {
            int row = m0 + wr * 64 + m * 16 + g * 4 + j;
            float s = 0.f;
#pragma unroll
            for (int n = 0; n < 4; ++n)
                s += __expf(acc[m][n][j]);
            s += __shfl_xor(s, 1, 64);
            s += __shfl_xor(s, 2, 64);
            s += __shfl_xor(s, 4, 64);
            s += __shfl_xor(s, 8, 64);
            if (l16 == 0) atomicAdd(&S[row], s);

            int id   = ids[row];
            int base = n0 + wc * 64 + l16;
#pragma unroll
            for (int n = 0; n < 4; ++n)
                if (id == base + n * 16) SEL[row] = acc[m][n][j];
        }
    }
}

// ---------------------------------------------------------------------------
// Zero S accumulators (8192 floats).
// ---------------------------------------------------------------------------
__global__ void grpo_init(float* __restrict__ p)
{
    p[blockIdx.x * 1024 + threadIdx.x] = 0.f;
}

// ---------------------------------------------------------------------------
// logp in-place over SEL: lp = SEL - log(S).
// ---------------------------------------------------------------------------
__global__ __launch_bounds__(1024)
void grpo_prep(const float* __restrict__ S_p, const float* __restrict__ S_r,
               float* __restrict__ lp_p, float* __restrict__ lp_r)
{
    int i = blockIdx.x * 1024 + threadIdx.x;
    lp_p[i] = lp_p[i] - logf(S_p[i]);
    lp_r[i] = lp_r[i] - logf(S_r[i]);
}

// ---------------------------------------------------------------------------
// Exact rank-819 threshold (k = int(4096*0.2) = 819), parallel over 64 CUs.
// Writes threshold into thr[0].
// ---------------------------------------------------------------------------
__global__ __launch_bounds__(64)
void grpo_thresh(const float* __restrict__ lp_r, float* __restrict__ thr)
{
    __shared__ float sh[NTOK];
    for (int i = threadIdx.x; i < NTOK; i += 64) sh[i] = lp_r[i];
    __syncthreads();
    const float v = sh[blockIdx.x * 64 + threadIdx.x];
    int lt = 0, eq = 0;
#pragma unroll 4
    for (int j = 0; j < NTOK; ++j) {
        float u = sh[j];
        lt += (u < v);
        eq += (u == v);
    }
    if (lt <= 818 && 818 < lt + eq) thr[0] = v;
}

// ---------------------------------------------------------------------------
// Final reductions -> 3 scalars. coef_1 == 1 exactly -> ppo term = -adv,
// clip_ratio = 0.
// ---------------------------------------------------------------------------
__global__ __launch_bounds__(1024)
void grpo_final(const float* __restrict__ lp_p, const float* __restrict__ lp_r,
                const float* __restrict__ thr,
                const float* __restrict__ am, const float* __restrict__ adv,
                float* __restrict__ out)
{
    __shared__ double red[3][16];
    const int tid = threadIdx.x;
    const float t = thr[0];

    double s_loss = 0.0, s_kl = 0.0, s_am = 0.0;
    for (int i = tid; i < NTOK; i += 1024) {
        float a  = am[i];
        float pr = lp_r[i], pp = lp_p[i];
        float lr = pr - pp;
        float k3 = expf(lr) - lr - 1.0f;
        float kl = (pr <= t) ? k3 * 5.0f : 0.0f;      // 1/percentile
        float ad = adv[i / TT];
        float ptl = -ad + 0.04f * kl;                  // BETA
        s_loss += (double)(ptl * a);
        s_kl   += (double)(kl * a);
        s_am   += (double)a;
    }
#pragma unroll
    for (int off = 32; off; off >>= 1) {
        s_loss += __shfl_down(s_loss, off, 64);
        s_kl   += __shfl_down(s_kl,   off, 64);
        s_am   += __shfl_down(s_am,   off, 64);
    }
    const int wid = tid >> 6;
    if ((tid & 63) == 0) { red[0][wid] = s_loss; red[1][wid] = s_kl; red[2][wid] = s_am; }
    __syncthreads();
    if (tid == 0) {
        double L = 0, K = 0, A = 0;
        for (int w = 0; w < 16; ++w) { L += red[0][w]; K += red[1][w]; A += red[2][w]; }
        double norm = A < 1.0 ? 1.0 : A;
        out[0] = (float)(L / norm);
        out[1] = (float)(K / norm);
        out[2] = 0.0f;
    }
}

extern "C" void kernel_launch(void* const* d_in, const int* in_sizes, int n_in,
                              void* d_out, int out_size, void* d_ws, size_t ws_size,
                              hipStream_t stream)
{
    const float* X   = (const float*)d_in[0];
    const float* W   = (const float*)d_in[1];
    const int*   ids = (const int*)  d_in[2];
    const float* am  = (const float*)d_in[3];
    const float* adv = (const float*)d_in[4];
    const float* Xr  = (const float*)d_in[5];
    const float* Wr  = (const float*)d_in[6];
    float* out = (float*)d_out;

    // ws small region (64 KB): S_p, S_r, SEL_p(->lp_p), SEL_r(->lp_r).
    // threshold scalar reuses S_p[0] after S is consumed.
    float* S_p  = (float*)d_ws;
    float* S_r  = S_p + NTOK;
    float* lp_p = S_r + NTOK;      // SEL_p, overwritten in-place by prep
    float* lp_r = lp_p + NTOK;     // SEL_r
    float* thr  = S_p;

    const size_t bf16_off = 65536;
    const size_t nX = (size_t)NTOK * HH, nW = (size_t)VV * HH;
    const size_t need = bf16_off + 2 * (nX + nW) * sizeof(bf16_t);

    hipLaunchKernelGGL(grpo_init, dim3(8), dim3(1024), 0, stream, S_p);

    dim3 grid(NTOK / BM, VV / BN);   // x (m-tile) fastest: 32 blocks share a W panel
    if (ws_size >= need) {
        bf16_t* Xb  = (bf16_t*)((char*)d_ws + bf16_off);
        bf16_t* Wb  = Xb + nX;
        bf16_t* Xrb = Wb + nW;
        bf16_t* Wrb = Xrb + nX;
        hipLaunchKernelGGL(grpo_cvt_bf16, dim3(1024), dim3(256), 0, stream, X,  Xb,  (int)(nX / 4));
        hipLaunchKernelGGL(grpo_cvt_bf16, dim3(2048), dim3(256), 0, stream, W,  Wb,  (int)(nW / 4));
        hipLaunchKernelGGL(grpo_cvt_bf16, dim3(1024), dim3(256), 0, stream, Xr, Xrb, (int)(nX / 4));
        hipLaunchKernelGGL(grpo_cvt_bf16, dim3(2048), dim3(256), 0, stream, Wr, Wrb, (int)(nW / 4));
        hipLaunchKernelGGL(grpo_gemm_lse_bf16, grid, dim3(256), 0, stream, Xb,  Wb,  ids, S_p, lp_p);
        hipLaunchKernelGGL(grpo_gemm_lse_bf16, grid, dim3(256), 0, stream, Xrb, Wrb, ids, S_r, lp_r);
    } else {
        hipLaunchKernelGGL(grpo_gemm_lse_f32, grid, dim3(256), 0, stream, X,  W,  ids, S_p, lp_p);
        hipLaunchKernelGGL(grpo_gemm_lse_f32, grid, dim3(256), 0, stream, Xr, Wr, ids, S_r, lp_r);
    }

    hipLaunchKernelGGL(grpo_prep,   dim3(4),  dim3(1024), 0, stream, S_p, S_r, lp_p, lp_r);
    hipLaunchKernelGGL(grpo_thresh, dim3(64), dim3(64),   0, stream, lp_r, thr);
    hipLaunchKernelGGL(grpo_final,  dim3(1),  dim3(1024), 0, stream, lp_p, lp_r, thr, am, adv, out);
}